// Round 1
// baseline (789.519 us; speedup 1.0000x reference)
//
#include <hip/hip_runtime.h>
#include <cmath>

#define N_NODES 50000
#define N_EDGES 800000
#define D_IN 256
#define D_HID 128
#define D_ENC 64

// ---------------- degree / norm ----------------
__global__ void deg_init_k(float* deg) {
    int i = blockIdx.x * blockDim.x + threadIdx.x;
    if (i < N_NODES) deg[i] = 1.0f;   // self-loop
}

__global__ void deg_count_k(const int* __restrict__ col, float* __restrict__ deg) {
    int stride = gridDim.x * blockDim.x;
    for (int e = blockIdx.x * blockDim.x + threadIdx.x; e < N_EDGES; e += stride)
        atomicAdd(&deg[col[e]], 1.0f);
}

__global__ void deg_fin_k(float* deg) {
    int i = blockIdx.x * blockDim.x + threadIdx.x;
    if (i < N_NODES) deg[i] = rsqrtf(deg[i]);   // deg >= 1 always
}

// ---------------- GEMM: H[n,NOUT] = X[n,K] @ W[K,NOUT] ----------------
// 256 threads/block, R rows per block. Lanes within a wave hold consecutive
// cols -> W loads coalesced; xs[][k] same addr across lanes -> LDS broadcast.
template<int K, int NOUT, int R>
__global__ void gemm_k(const float* __restrict__ X, const float* __restrict__ W,
                       float* __restrict__ H, int n) {
    constexpr int NG = 256 / NOUT;   // col-groups
    constexpr int RG = R / NG;       // rows per group
    __shared__ float xs[R][K];
    int row0 = blockIdx.x * R;
    for (int idx = threadIdx.x; idx < R * K; idx += 256) {
        int r = idx / K, k = idx % K;
        int gr = row0 + r;
        xs[r][k] = (gr < n) ? X[(size_t)gr * K + k] : 0.0f;
    }
    __syncthreads();
    int col = threadIdx.x % NOUT;
    int g   = threadIdx.x / NOUT;
    float acc[RG];
#pragma unroll
    for (int j = 0; j < RG; ++j) acc[j] = 0.0f;
#pragma unroll 4
    for (int k = 0; k < K; ++k) {
        float w = W[k * NOUT + col];
#pragma unroll
        for (int j = 0; j < RG; ++j) acc[j] += xs[g * RG + j][k] * w;
    }
#pragma unroll
    for (int j = 0; j < RG; ++j) {
        int gr = row0 + g * RG + j;
        if (gr < n) H[(size_t)gr * NOUT + col] = acc[j];
    }
}

// ---------------- edge scatter: A[c,:] += dinv[r]*dinv[c] * H[r,:] ----------------
template<int D>
__global__ void scatter_k(const float* __restrict__ H, const int* __restrict__ rows,
                          const int* __restrict__ cols, const float* __restrict__ dinv,
                          float* __restrict__ A) {
    constexpr int EPB = 256 / D;
    int d   = threadIdx.x % D;
    int sub = threadIdx.x / D;
    int estride = gridDim.x * EPB;
    for (int e = blockIdx.x * EPB + sub; e < N_EDGES; e += estride) {
        int r = rows[e], c = cols[e];
        float w = dinv[r] * dinv[c];
        atomicAdd(&A[(size_t)c * D + d], H[(size_t)r * D + d] * w);
    }
}

// ---------------- epilogue 1: A = relu(A + dinv^2*H + b)  (in place) ----------------
__global__ void epi1_k(float* __restrict__ A, const float* __restrict__ H,
                       const float* __restrict__ dinv, const float* __restrict__ b) {
    size_t i = (size_t)blockIdx.x * blockDim.x + threadIdx.x;
    if (i < (size_t)N_NODES * D_HID) {
        int node = (int)(i / D_HID);
        int d    = (int)(i % D_HID);
        float di = dinv[node];
        float v  = A[i] + di * di * H[i] + b[d];
        A[i] = v > 0.0f ? v : 0.0f;
    }
}

// ---------------- final: out = sigmoid((A2 + dinv^2*H2 + b2) @ Wfc + bfc) ----------------
// one wave (64 lanes) per node, 4 nodes per 256-thread block
__global__ void final_k(const float* __restrict__ A2, const float* __restrict__ H2,
                        const float* __restrict__ dinv, const float* __restrict__ b2,
                        const float* __restrict__ Wfc, const float* __restrict__ bfc,
                        float* __restrict__ out) {
    int node = blockIdx.x * 4 + (threadIdx.x >> 6);
    int d    = threadIdx.x & 63;
    if (node >= N_NODES) return;
    float di = dinv[node];
    size_t idx = (size_t)node * D_ENC + d;
    float v = A2[idx] + di * di * H2[idx] + b2[d];
    float p = v * Wfc[d];
#pragma unroll
    for (int off = 32; off; off >>= 1) p += __shfl_down(p, off, 64);
    if (d == 0) out[node] = 1.0f / (1.0f + expf(-(p + bfc[0])));
}

extern "C" void kernel_launch(void* const* d_in, const int* in_sizes, int n_in,
                              void* d_out, int out_size, void* d_ws, size_t ws_size,
                              hipStream_t stream) {
    const float* x   = (const float*)d_in[0];
    const int*   ei  = (const int*)d_in[1];     // [2, E] int32
    const float* W1  = (const float*)d_in[2];
    const float* b1  = (const float*)d_in[3];
    const float* W2  = (const float*)d_in[4];
    const float* b2  = (const float*)d_in[5];
    const float* Wfc = (const float*)d_in[6];
    const float* bfc = (const float*)d_in[7];
    float* out = (float*)d_out;

    const int* rows = ei;             // sources
    const int* cols = ei + N_EDGES;   // targets

    // workspace layout (floats)
    float* ws = (float*)d_ws;
    float* dinv = ws;                              // 50048
    float* h1   = ws + 50048;                      // 6.4M
    float* a1   = h1 + (size_t)N_NODES * D_HID;    // 6.4M
    float* h2   = a1 + (size_t)N_NODES * D_HID;    // 3.2M
    float* a2   = h2 + (size_t)N_NODES * D_ENC;    // 3.2M

    // zero the accumulators (ws is poisoned 0xAA before every call)
    hipMemsetAsync(a1, 0, (size_t)N_NODES * D_HID * sizeof(float), stream);
    hipMemsetAsync(a2, 0, (size_t)N_NODES * D_ENC * sizeof(float), stream);

    // degrees -> dinv
    deg_init_k<<<(N_NODES + 255) / 256, 256, 0, stream>>>(dinv);
    deg_count_k<<<1024, 256, 0, stream>>>(cols, dinv);
    deg_fin_k<<<(N_NODES + 255) / 256, 256, 0, stream>>>(dinv);

    // layer 1: h1 = x @ W1 ; a1 = scatter ; a1 = relu(a1 + dinv^2 h1 + b1)
    gemm_k<D_IN, D_HID, 8><<<(N_NODES + 7) / 8, 256, 0, stream>>>(x, W1, h1, N_NODES);
    scatter_k<D_HID><<<4096, 256, 0, stream>>>(h1, rows, cols, dinv, a1);
    epi1_k<<<(N_NODES * D_HID + 255) / 256, 256, 0, stream>>>(a1, h1, dinv, b1);

    // layer 2: h2 = a1 @ W2 ; a2 = scatter ; fused fc+sigmoid
    gemm_k<D_HID, D_ENC, 8><<<(N_NODES + 7) / 8, 256, 0, stream>>>(a1, W2, h2, N_NODES);
    scatter_k<D_ENC><<<4096, 256, 0, stream>>>(h2, rows, cols, dinv, a2);
    final_k<<<(N_NODES + 3) / 4, 256, 0, stream>>>(a2, h2, dinv, b2, Wfc, bfc, out);
}

// Round 2
// 536.880 us; speedup vs baseline: 1.4706x; 1.4706x over previous
//
#include <hip/hip_runtime.h>
#include <cmath>

#define N_NODES 50000
#define N_EDGES 800000
#define D_IN 256
#define D_HID 128
#define D_ENC 64
#define SCAN_B 1024

// ---------------- CSR build: count -> scan -> fill ----------------
__global__ void count_k(const int* __restrict__ cols, int* __restrict__ cnt) {
    int stride = gridDim.x * blockDim.x;
    for (int e = blockIdx.x * blockDim.x + threadIdx.x; e < N_EDGES; e += stride)
        atomicAdd(&cnt[cols[e]], 1);
}

__global__ void scan_block_k(const int* __restrict__ cnt, int* __restrict__ rowptr,
                             int* __restrict__ bsum) {
    __shared__ int s[SCAN_B];
    int i = blockIdx.x * SCAN_B + threadIdx.x;
    int v = (i < N_NODES) ? cnt[i] : 0;
    s[threadIdx.x] = v;
    __syncthreads();
    for (int off = 1; off < SCAN_B; off <<= 1) {
        int t = (threadIdx.x >= off) ? s[threadIdx.x - off] : 0;
        __syncthreads();
        s[threadIdx.x] += t;
        __syncthreads();
    }
    if (i < N_NODES) rowptr[i] = s[threadIdx.x] - v;   // exclusive
    if (threadIdx.x == SCAN_B - 1) bsum[blockIdx.x] = s[threadIdx.x];
}

__global__ void scan_top_k(int* __restrict__ bsum, int nb) {
    if (threadIdx.x == 0 && blockIdx.x == 0) {
        int acc = 0;
        for (int i = 0; i < nb; ++i) { int v = bsum[i]; bsum[i] = acc; acc += v; }
    }
}

// rowptr += block offset; dinv = rsqrt(deg+1); cursor (=cnt reused) = rowptr
__global__ void scan_add_k(int* __restrict__ cnt, int* __restrict__ rowptr,
                           const int* __restrict__ bsum, float* __restrict__ dinv) {
    int i = blockIdx.x * blockDim.x + threadIdx.x;
    if (i < N_NODES) {
        int rp = rowptr[i] + bsum[i / SCAN_B];
        rowptr[i] = rp;
        dinv[i] = rsqrtf((float)(cnt[i] + 1));   // +1 self-loop
        cnt[i] = rp;                              // becomes fill cursor
    }
}

__global__ void fill_k(const int* __restrict__ rows, const int* __restrict__ cols,
                       int* __restrict__ cursor, int* __restrict__ srcs) {
    int stride = gridDim.x * blockDim.x;
    for (int e = blockIdx.x * blockDim.x + threadIdx.x; e < N_EDGES; e += stride) {
        int p = atomicAdd(&cursor[cols[e]], 1);
        srcs[p] = rows[e];
    }
}

// ---------------- GEMM: H[n,NOUT] = X[n,K] @ W[K,NOUT] ----------------
template<int K, int NOUT, int R>
__global__ void gemm_k(const float* __restrict__ X, const float* __restrict__ W,
                       float* __restrict__ H, int n) {
    constexpr int NG = 256 / NOUT;
    constexpr int RG = R / NG;
    __shared__ float xs[R][K];
    int row0 = blockIdx.x * R;
    for (int idx = threadIdx.x; idx < R * K; idx += 256) {
        int r = idx / K, k = idx % K;
        int gr = row0 + r;
        xs[r][k] = (gr < n) ? X[(size_t)gr * K + k] : 0.0f;
    }
    __syncthreads();
    int col = threadIdx.x % NOUT;
    int g   = threadIdx.x / NOUT;
    float acc[RG];
#pragma unroll
    for (int j = 0; j < RG; ++j) acc[j] = 0.0f;
#pragma unroll 4
    for (int k = 0; k < K; ++k) {
        float w = W[k * NOUT + col];
#pragma unroll
        for (int j = 0; j < RG; ++j) acc[j] += xs[g * RG + j][k] * w;
    }
#pragma unroll
    for (int j = 0; j < RG; ++j) {
        int gr = row0 + g * RG + j;
        if (gr < n) H[(size_t)gr * NOUT + col] = acc[j];
    }
}

// ---------------- gather layer 1 (fused bias + ReLU) ----------------
// 2 nodes per 256-block, 128 threads (=channels) per node; wave-uniform loop.
__global__ void gather1_k(const float* __restrict__ h1, const int* __restrict__ rowptr,
                          const int* __restrict__ srcs, const float* __restrict__ dinv,
                          const float* __restrict__ b, float* __restrict__ a1) {
    int node = blockIdx.x * 2 + (threadIdx.x >> 7);
    int d    = threadIdx.x & 127;
    if (node >= N_NODES) return;
    int beg = rowptr[node];
    int end = (node + 1 < N_NODES) ? rowptr[node + 1] : N_EDGES;
    float acc = 0.0f;
    for (int i = beg; i < end; ++i) {
        int s = srcs[i];
        acc += dinv[s] * h1[(size_t)s * D_HID + d];
    }
    float di = dinv[node];
    float v  = di * (acc + di * h1[(size_t)node * D_HID + d]) + b[d];
    a1[(size_t)node * D_HID + d] = v > 0.0f ? v : 0.0f;
}

// ---------------- gather layer 2 (fused bias + FC dot + sigmoid) ----------------
// 4 nodes per 256-block, one wave (=64 channels) per node.
__global__ void gather2_k(const float* __restrict__ h2, const int* __restrict__ rowptr,
                          const int* __restrict__ srcs, const float* __restrict__ dinv,
                          const float* __restrict__ b2, const float* __restrict__ Wfc,
                          const float* __restrict__ bfc, float* __restrict__ out) {
    int node = blockIdx.x * 4 + (threadIdx.x >> 6);
    int d    = threadIdx.x & 63;
    if (node >= N_NODES) return;
    int beg = rowptr[node];
    int end = (node + 1 < N_NODES) ? rowptr[node + 1] : N_EDGES;
    float acc = 0.0f;
    for (int i = beg; i < end; ++i) {
        int s = srcs[i];
        acc += dinv[s] * h2[(size_t)s * D_ENC + d];
    }
    float di = dinv[node];
    float v  = di * (acc + di * h2[(size_t)node * D_ENC + d]) + b2[d];
    float p  = v * Wfc[d];
#pragma unroll
    for (int off = 32; off; off >>= 1) p += __shfl_down(p, off, 64);
    if (d == 0) out[node] = 1.0f / (1.0f + expf(-(p + bfc[0])));
}

extern "C" void kernel_launch(void* const* d_in, const int* in_sizes, int n_in,
                              void* d_out, int out_size, void* d_ws, size_t ws_size,
                              hipStream_t stream) {
    const float* x   = (const float*)d_in[0];
    const int*   ei  = (const int*)d_in[1];     // [2, E] int32
    const float* W1  = (const float*)d_in[2];
    const float* b1  = (const float*)d_in[3];
    const float* W2  = (const float*)d_in[4];
    const float* b2  = (const float*)d_in[5];
    const float* Wfc = (const float*)d_in[6];
    const float* bfc = (const float*)d_in[7];
    float* out = (float*)d_out;

    const int* rows = ei;             // sources
    const int* cols = ei + N_EDGES;   // targets

    // workspace layout (all 4-byte elements)
    float* ws     = (float*)d_ws;
    float* dinv   = ws;                                  // 50048
    int*   cnt    = (int*)(ws + 50048);                  // 50048 (later cursor)
    int*   rowptr = cnt + 50048;                         // 50048
    int*   bsum   = rowptr + 50048;                      // 64
    int*   srcs   = bsum + 64;                           // 800000
    float* h1     = (float*)(srcs + N_EDGES);            // 6.4M
    float* a1     = h1 + (size_t)N_NODES * D_HID;        // 6.4M
    float* h2     = a1 + (size_t)N_NODES * D_HID;        // 3.2M

    const int NB = (N_NODES + SCAN_B - 1) / SCAN_B;      // 49

    // ---- CSR build ----
    hipMemsetAsync(cnt, 0, N_NODES * sizeof(int), stream);
    count_k<<<1024, 256, 0, stream>>>(cols, cnt);
    scan_block_k<<<NB, SCAN_B, 0, stream>>>(cnt, rowptr, bsum);
    scan_top_k<<<1, 64, 0, stream>>>(bsum, NB);
    scan_add_k<<<(N_NODES + 255) / 256, 256, 0, stream>>>(cnt, rowptr, bsum, dinv);
    fill_k<<<1024, 256, 0, stream>>>(rows, cols, cnt, srcs);

    // ---- layer 1 ----
    gemm_k<D_IN, D_HID, 8><<<(N_NODES + 7) / 8, 256, 0, stream>>>(x, W1, h1, N_NODES);
    gather1_k<<<(N_NODES + 1) / 2, 256, 0, stream>>>(h1, rowptr, srcs, dinv, b1, a1);

    // ---- layer 2 + FC + sigmoid ----
    gemm_k<D_HID, D_ENC, 8><<<(N_NODES + 7) / 8, 256, 0, stream>>>(a1, W2, h2, N_NODES);
    gather2_k<<<(N_NODES + 3) / 4, 256, 0, stream>>>(h2, rowptr, srcs, dinv, b2, Wfc, bfc, out);
}

// Round 3
// 404.064 us; speedup vs baseline: 1.9539x; 1.3287x over previous
//
#include <hip/hip_runtime.h>
#include <cmath>

#define N_NODES 50000
#define N_EDGES 800000
#define D_IN 256
#define D_HID 128
#define D_ENC 64
#define SCAN_B 1024

// ---------------- CSR build: count -> scan -> fill ----------------
__global__ void count_k(const int* __restrict__ cols, int* __restrict__ cnt) {
    int stride = gridDim.x * blockDim.x;
    for (int e = blockIdx.x * blockDim.x + threadIdx.x; e < N_EDGES; e += stride)
        atomicAdd(&cnt[cols[e]], 1);
}

__global__ void scan_block_k(const int* __restrict__ cnt, int* __restrict__ rowptr,
                             int* __restrict__ bsum) {
    __shared__ int s[SCAN_B];
    int i = blockIdx.x * SCAN_B + threadIdx.x;
    int v = (i < N_NODES) ? cnt[i] : 0;
    s[threadIdx.x] = v;
    __syncthreads();
    for (int off = 1; off < SCAN_B; off <<= 1) {
        int t = (threadIdx.x >= off) ? s[threadIdx.x - off] : 0;
        __syncthreads();
        s[threadIdx.x] += t;
        __syncthreads();
    }
    if (i < N_NODES) rowptr[i] = s[threadIdx.x] - v;   // exclusive
    if (threadIdx.x == SCAN_B - 1) bsum[blockIdx.x] = s[threadIdx.x];
}

__global__ void scan_top_k(int* __restrict__ bsum, int nb) {
    if (threadIdx.x == 0 && blockIdx.x == 0) {
        int acc = 0;
        for (int i = 0; i < nb; ++i) { int v = bsum[i]; bsum[i] = acc; acc += v; }
    }
}

__global__ void scan_add_k(int* __restrict__ cnt, int* __restrict__ rowptr,
                           const int* __restrict__ bsum, float* __restrict__ dinv) {
    int i = blockIdx.x * blockDim.x + threadIdx.x;
    if (i < N_NODES) {
        int rp = rowptr[i] + bsum[i / SCAN_B];
        rowptr[i] = rp;
        dinv[i] = rsqrtf((float)(cnt[i] + 1));   // +1 self-loop
        cnt[i] = rp;                              // becomes fill cursor
    }
}

__global__ void fill_k(const int* __restrict__ rows, const int* __restrict__ cols,
                       int* __restrict__ cursor, int* __restrict__ srcs) {
    int stride = gridDim.x * blockDim.x;
    for (int e = blockIdx.x * blockDim.x + threadIdx.x; e < N_EDGES; e += stride) {
        int p = atomicAdd(&cursor[cols[e]], 1);
        srcs[p] = rows[e];
    }
}

// ---------------- GEMM: H[r,:] = dinv[r] * (X[r,:] @ W)  ----------------
template<int K, int NOUT, int R>
__global__ void gemm_k(const float* __restrict__ X, const float* __restrict__ W,
                       const float* __restrict__ dinv, float* __restrict__ H, int n) {
    constexpr int NG = 256 / NOUT;
    constexpr int RG = R / NG;
    __shared__ float xs[R][K];
    int row0 = blockIdx.x * R;
    // float4 staging into LDS
    const float4* X4 = (const float4*)X;
    for (int idx = threadIdx.x; idx < R * K / 4; idx += 256) {
        int r = idx / (K / 4), k4 = idx % (K / 4);
        int gr = row0 + r;
        float4 v = (gr < n) ? X4[(size_t)gr * (K / 4) + k4] : float4{0, 0, 0, 0};
        xs[r][k4 * 4 + 0] = v.x; xs[r][k4 * 4 + 1] = v.y;
        xs[r][k4 * 4 + 2] = v.z; xs[r][k4 * 4 + 3] = v.w;
    }
    __syncthreads();
    int col = threadIdx.x % NOUT;
    int g   = threadIdx.x / NOUT;
    float acc[RG];
#pragma unroll
    for (int j = 0; j < RG; ++j) acc[j] = 0.0f;
#pragma unroll 4
    for (int k = 0; k < K; ++k) {
        float w = W[k * NOUT + col];
#pragma unroll
        for (int j = 0; j < RG; ++j) acc[j] += xs[g * RG + j][k] * w;
    }
#pragma unroll
    for (int j = 0; j < RG; ++j) {
        int gr = row0 + g * RG + j;
        if (gr < n) H[(size_t)gr * NOUT + col] = acc[j] * dinv[gr];
    }
}

// ---------------- gather layer 1: a1 = relu(di*(sum_s hs[s] + hs[c]) + b) ----------------
// 32 lanes per node (float4 over 128 ch), 8 nodes per 256-block, unroll x4.
__global__ void gather1_k(const float4* __restrict__ hs, const int* __restrict__ rowptr,
                          const int* __restrict__ srcs, const float* __restrict__ dinv,
                          const float4* __restrict__ b4, float4* __restrict__ a1) {
    int node = blockIdx.x * 8 + (threadIdx.x >> 5);
    int d4   = threadIdx.x & 31;
    if (node >= N_NODES) return;
    int beg = rowptr[node];
    int end = (node + 1 < N_NODES) ? rowptr[node + 1] : N_EDGES;
    float4 a0 = {0, 0, 0, 0}, a1v = {0, 0, 0, 0}, a2v = {0, 0, 0, 0}, a3v = {0, 0, 0, 0};
    int i = beg;
    for (; i + 4 <= end; i += 4) {
        int s0 = srcs[i], s1 = srcs[i + 1], s2 = srcs[i + 2], s3 = srcs[i + 3];
        float4 v0 = hs[(size_t)s0 * 32 + d4];
        float4 v1 = hs[(size_t)s1 * 32 + d4];
        float4 v2 = hs[(size_t)s2 * 32 + d4];
        float4 v3 = hs[(size_t)s3 * 32 + d4];
        a0.x += v0.x; a0.y += v0.y; a0.z += v0.z; a0.w += v0.w;
        a1v.x += v1.x; a1v.y += v1.y; a1v.z += v1.z; a1v.w += v1.w;
        a2v.x += v2.x; a2v.y += v2.y; a2v.z += v2.z; a2v.w += v2.w;
        a3v.x += v3.x; a3v.y += v3.y; a3v.z += v3.z; a3v.w += v3.w;
    }
    for (; i < end; ++i) {
        float4 v = hs[(size_t)srcs[i] * 32 + d4];
        a0.x += v.x; a0.y += v.y; a0.z += v.z; a0.w += v.w;
    }
    float4 vc = hs[(size_t)node * 32 + d4];   // self-loop (already dinv-scaled)
    float4 acc;
    acc.x = a0.x + a1v.x + a2v.x + a3v.x + vc.x;
    acc.y = a0.y + a1v.y + a2v.y + a3v.y + vc.y;
    acc.z = a0.z + a1v.z + a2v.z + a3v.z + vc.z;
    acc.w = a0.w + a1v.w + a2v.w + a3v.w + vc.w;
    float di = dinv[node];
    float4 b = b4[d4];
    float4 r;
    r.x = fmaxf(di * acc.x + b.x, 0.0f);
    r.y = fmaxf(di * acc.y + b.y, 0.0f);
    r.z = fmaxf(di * acc.z + b.z, 0.0f);
    r.w = fmaxf(di * acc.w + b.w, 0.0f);
    a1[(size_t)node * 32 + d4] = r;
}

// ---------------- gather layer 2 + FC + sigmoid ----------------
// 32 lanes per node (float2 over 64 ch), 8 nodes per 256-block, unroll x4.
__global__ void gather2_k(const float2* __restrict__ hs, const int* __restrict__ rowptr,
                          const int* __restrict__ srcs, const float* __restrict__ dinv,
                          const float2* __restrict__ b2, const float2* __restrict__ Wfc,
                          const float* __restrict__ bfc, float* __restrict__ out) {
    int node = blockIdx.x * 8 + (threadIdx.x >> 5);
    int d2   = threadIdx.x & 31;
    if (node >= N_NODES) return;
    int beg = rowptr[node];
    int end = (node + 1 < N_NODES) ? rowptr[node + 1] : N_EDGES;
    float2 a0 = {0, 0}, a1v = {0, 0}, a2v = {0, 0}, a3v = {0, 0};
    int i = beg;
    for (; i + 4 <= end; i += 4) {
        int s0 = srcs[i], s1 = srcs[i + 1], s2 = srcs[i + 2], s3 = srcs[i + 3];
        float2 v0 = hs[(size_t)s0 * 32 + d2];
        float2 v1 = hs[(size_t)s1 * 32 + d2];
        float2 v2 = hs[(size_t)s2 * 32 + d2];
        float2 v3 = hs[(size_t)s3 * 32 + d2];
        a0.x += v0.x; a0.y += v0.y;
        a1v.x += v1.x; a1v.y += v1.y;
        a2v.x += v2.x; a2v.y += v2.y;
        a3v.x += v3.x; a3v.y += v3.y;
    }
    for (; i < end; ++i) {
        float2 v = hs[(size_t)srcs[i] * 32 + d2];
        a0.x += v.x; a0.y += v.y;
    }
    float2 vc = hs[(size_t)node * 32 + d2];
    float accx = a0.x + a1v.x + a2v.x + a3v.x + vc.x;
    float accy = a0.y + a1v.y + a2v.y + a3v.y + vc.y;
    float di = dinv[node];
    float2 b = b2[d2];
    float2 w = Wfc[d2];
    float vx = di * accx + b.x;
    float vy = di * accy + b.y;
    float p = vx * w.x + vy * w.y;
#pragma unroll
    for (int off = 16; off; off >>= 1) p += __shfl_down(p, off, 32);
    if (d2 == 0) out[node] = 1.0f / (1.0f + expf(-(p + bfc[0])));
}

extern "C" void kernel_launch(void* const* d_in, const int* in_sizes, int n_in,
                              void* d_out, int out_size, void* d_ws, size_t ws_size,
                              hipStream_t stream) {
    const float* x   = (const float*)d_in[0];
    const int*   ei  = (const int*)d_in[1];     // [2, E] int32
    const float* W1  = (const float*)d_in[2];
    const float* b1  = (const float*)d_in[3];
    const float* W2  = (const float*)d_in[4];
    const float* b2  = (const float*)d_in[5];
    const float* Wfc = (const float*)d_in[6];
    const float* bfc = (const float*)d_in[7];
    float* out = (float*)d_out;

    const int* rows = ei;             // sources
    const int* cols = ei + N_EDGES;   // targets

    // workspace layout (all 4-byte elements)
    float* ws     = (float*)d_ws;
    float* dinv   = ws;                                  // 50048
    int*   cnt    = (int*)(ws + 50048);                  // 50048 (later cursor)
    int*   rowptr = cnt + 50048;                         // 50048
    int*   bsum   = rowptr + 50048;                      // 64
    int*   srcs   = bsum + 64;                           // 800000
    float* h1     = (float*)(srcs + N_EDGES);            // 6.4M  (dinv-scaled)
    float* a1     = h1 + (size_t)N_NODES * D_HID;        // 6.4M
    float* h2     = a1 + (size_t)N_NODES * D_HID;        // 3.2M  (dinv-scaled)

    const int NB = (N_NODES + SCAN_B - 1) / SCAN_B;      // 49

    // ---- CSR build ----
    hipMemsetAsync(cnt, 0, N_NODES * sizeof(int), stream);
    count_k<<<1024, 256, 0, stream>>>(cols, cnt);
    scan_block_k<<<NB, SCAN_B, 0, stream>>>(cnt, rowptr, bsum);
    scan_top_k<<<1, 64, 0, stream>>>(bsum, NB);
    scan_add_k<<<(N_NODES + 255) / 256, 256, 0, stream>>>(cnt, rowptr, bsum, dinv);
    fill_k<<<1024, 256, 0, stream>>>(rows, cols, cnt, srcs);

    // ---- layer 1 ----
    gemm_k<D_IN, D_HID, 8><<<(N_NODES + 7) / 8, 256, 0, stream>>>(x, W1, dinv, h1, N_NODES);
    gather1_k<<<(N_NODES + 7) / 8, 256, 0, stream>>>((const float4*)h1, rowptr, srcs, dinv,
                                                     (const float4*)b1, (float4*)a1);

    // ---- layer 2 + FC + sigmoid ----
    gemm_k<D_HID, D_ENC, 8><<<(N_NODES + 7) / 8, 256, 0, stream>>>(a1, W2, dinv, h2, N_NODES);
    gather2_k<<<(N_NODES + 7) / 8, 256, 0, stream>>>((const float2*)h2, rowptr, srcs, dinv,
                                                     (const float2*)b2, (const float2*)Wfc,
                                                     bfc, out);
}

// Round 4
// 317.631 us; speedup vs baseline: 2.4856x; 1.2721x over previous
//
#include <hip/hip_runtime.h>
#include <cmath>

#define N_NODES 50000
#define N_EDGES 800000
#define D_IN 256
#define D_HID 128
#define D_ENC 64
#define SCAN_B 1024

typedef short short8 __attribute__((ext_vector_type(8)));
typedef float floatx4 __attribute__((ext_vector_type(4)));

static __device__ __forceinline__ unsigned short f2bf(float f) {
    unsigned int u = __float_as_uint(f);
    unsigned int r = (u + 0x7FFFu + ((u >> 16) & 1u)) >> 16;   // RNE
    return (unsigned short)r;
}

// ---------------- CSR build: count -> scan -> fill ----------------
__global__ void count_k(const int* __restrict__ cols, int* __restrict__ cnt) {
    int stride = gridDim.x * blockDim.x;
    for (int e = blockIdx.x * blockDim.x + threadIdx.x; e < N_EDGES; e += stride)
        atomicAdd(&cnt[cols[e]], 1);
}

__global__ void scan_block_k(const int* __restrict__ cnt, int* __restrict__ rowptr,
                             int* __restrict__ bsum) {
    __shared__ int s[SCAN_B];
    int i = blockIdx.x * SCAN_B + threadIdx.x;
    int v = (i < N_NODES) ? cnt[i] : 0;
    s[threadIdx.x] = v;
    __syncthreads();
    for (int off = 1; off < SCAN_B; off <<= 1) {
        int t = (threadIdx.x >= off) ? s[threadIdx.x - off] : 0;
        __syncthreads();
        s[threadIdx.x] += t;
        __syncthreads();
    }
    if (i < N_NODES) rowptr[i] = s[threadIdx.x] - v;   // exclusive
    if (threadIdx.x == SCAN_B - 1) bsum[blockIdx.x] = s[threadIdx.x];
}

__global__ void scan_top_k(int* __restrict__ bsum, int nb) {
    if (threadIdx.x == 0 && blockIdx.x == 0) {
        int acc = 0;
        for (int i = 0; i < nb; ++i) { int v = bsum[i]; bsum[i] = acc; acc += v; }
    }
}

__global__ void scan_add_k(int* __restrict__ cnt, int* __restrict__ rowptr,
                           const int* __restrict__ bsum, float* __restrict__ dinv) {
    int i = blockIdx.x * blockDim.x + threadIdx.x;
    if (i < N_NODES) {
        int rp = rowptr[i] + bsum[i / SCAN_B];
        rowptr[i] = rp;
        dinv[i] = rsqrtf((float)(cnt[i] + 1));   // +1 self-loop
        cnt[i] = rp;                              // becomes fill cursor
    }
}

__global__ void fill_k(const int* __restrict__ rows, const int* __restrict__ cols,
                       int* __restrict__ cursor, int* __restrict__ srcs) {
    int stride = gridDim.x * blockDim.x;
    for (int e = blockIdx.x * blockDim.x + threadIdx.x; e < N_EDGES; e += stride) {
        int p = atomicAdd(&cursor[cols[e]], 1);
        srcs[p] = rows[e];
    }
}

// ---------------- W pre-swizzle into B-fragment layout (bf16) ----------------
// frag t=(ct*KS+ks)*64+lane holds B[k=ks*32+quad*8+j][n=ct*16+(lane&15)], j=0..7
template<int K, int N>
__global__ void wsw_k(const float* __restrict__ W, unsigned short* __restrict__ Wsw) {
    constexpr int KS = K / 32, CT = N / 16;
    int t = blockIdx.x * blockDim.x + threadIdx.x;
    if (t >= CT * KS * 64) return;
    int lane = t & 63;
    int ks   = (t >> 6) % KS;
    int ct   = (t >> 6) / KS;
    int m = lane & 15, quad = lane >> 4;
    int kbase = ks * 32 + quad * 8;
    int col   = ct * 16 + m;
#pragma unroll
    for (int j = 0; j < 8; ++j)
        Wsw[t * 8 + j] = f2bf(W[(size_t)(kbase + j) * N + col]);
}

// ---------------- MFMA GEMM: H[r,:] = dinv[r] * (X[r,:] @ W) ----------------
// 64 rows/block, 4 waves x 16 rows, bf16 16x16x32 MFMA, fp32 X converted in staging.
template<int K, int N>
__global__ __launch_bounds__(256) void gemm_mfma_k(const float* __restrict__ X,
                                                   const unsigned short* __restrict__ Wsw,
                                                   const float* __restrict__ dinv,
                                                   float* __restrict__ H, int n) {
    constexpr int KS = K / 32, CT = N / 16, KP = K + 8;
    __shared__ unsigned short As[64 * KP];
    int row0 = blockIdx.x * 64;
    // stage X fp32 -> bf16 LDS
    const float4* X4 = (const float4*)X;
    constexpr int NF4 = 64 * (K / 4);
    for (int idx = threadIdx.x; idx < NF4; idx += 256) {
        int r = idx / (K / 4), c4 = idx % (K / 4);
        int gr = row0 + r;
        float4 v = (gr < n) ? X4[(size_t)gr * (K / 4) + c4] : float4{0, 0, 0, 0};
        ushort4 p;
        p.x = f2bf(v.x); p.y = f2bf(v.y); p.z = f2bf(v.z); p.w = f2bf(v.w);
        *(ushort4*)&As[r * KP + c4 * 4] = p;
    }
    __syncthreads();

    int w    = threadIdx.x >> 6;
    int lane = threadIdx.x & 63;
    int m    = lane & 15;
    int quad = lane >> 4;

    floatx4 acc[CT];
#pragma unroll
    for (int ct = 0; ct < CT; ++ct)
#pragma unroll
        for (int i = 0; i < 4; ++i) acc[ct][i] = 0.0f;

#pragma unroll
    for (int ks = 0; ks < KS; ++ks) {
        short8 af = *(const short8*)&As[(w * 16 + m) * KP + ks * 32 + quad * 8];
#pragma unroll
        for (int ct = 0; ct < CT; ++ct) {
            short8 bf = *(const short8*)&Wsw[(size_t)((ct * KS + ks) * 64 + lane) * 8];
            acc[ct] = __builtin_amdgcn_mfma_f32_16x16x32_bf16(af, bf, acc[ct], 0, 0, 0);
        }
    }

    int rbase = row0 + w * 16 + quad * 4;
    float dv[4];
#pragma unroll
    for (int reg = 0; reg < 4; ++reg) {
        int r = rbase + reg;
        dv[reg] = (r < n) ? dinv[r] : 0.0f;
    }
#pragma unroll
    for (int ct = 0; ct < CT; ++ct)
#pragma unroll
        for (int reg = 0; reg < 4; ++reg) {
            int r = rbase + reg;
            if (r < n) H[(size_t)r * N + ct * 16 + m] = acc[ct][reg] * dv[reg];
        }
}

// ---------------- gather layer 1: a1 = relu(di*(sum_s hs[s] + hs[c]) + b) ----------------
__global__ void gather1_k(const float4* __restrict__ hs, const int* __restrict__ rowptr,
                          const int* __restrict__ srcs, const float* __restrict__ dinv,
                          const float4* __restrict__ b4, float4* __restrict__ a1) {
    int node = blockIdx.x * 8 + (threadIdx.x >> 5);
    int d4   = threadIdx.x & 31;
    if (node >= N_NODES) return;
    int beg = rowptr[node];
    int end = (node + 1 < N_NODES) ? rowptr[node + 1] : N_EDGES;
    float4 a0 = {0, 0, 0, 0}, a1v = {0, 0, 0, 0}, a2v = {0, 0, 0, 0}, a3v = {0, 0, 0, 0};
    int i = beg;
    for (; i + 4 <= end; i += 4) {
        int s0 = srcs[i], s1 = srcs[i + 1], s2 = srcs[i + 2], s3 = srcs[i + 3];
        float4 v0 = hs[(size_t)s0 * 32 + d4];
        float4 v1 = hs[(size_t)s1 * 32 + d4];
        float4 v2 = hs[(size_t)s2 * 32 + d4];
        float4 v3 = hs[(size_t)s3 * 32 + d4];
        a0.x += v0.x; a0.y += v0.y; a0.z += v0.z; a0.w += v0.w;
        a1v.x += v1.x; a1v.y += v1.y; a1v.z += v1.z; a1v.w += v1.w;
        a2v.x += v2.x; a2v.y += v2.y; a2v.z += v2.z; a2v.w += v2.w;
        a3v.x += v3.x; a3v.y += v3.y; a3v.z += v3.z; a3v.w += v3.w;
    }
    for (; i < end; ++i) {
        float4 v = hs[(size_t)srcs[i] * 32 + d4];
        a0.x += v.x; a0.y += v.y; a0.z += v.z; a0.w += v.w;
    }
    float4 vc = hs[(size_t)node * 32 + d4];   // self-loop (already dinv-scaled)
    float4 acc;
    acc.x = a0.x + a1v.x + a2v.x + a3v.x + vc.x;
    acc.y = a0.y + a1v.y + a2v.y + a3v.y + vc.y;
    acc.z = a0.z + a1v.z + a2v.z + a3v.z + vc.z;
    acc.w = a0.w + a1v.w + a2v.w + a3v.w + vc.w;
    float di = dinv[node];
    float4 b = b4[d4];
    float4 r;
    r.x = fmaxf(di * acc.x + b.x, 0.0f);
    r.y = fmaxf(di * acc.y + b.y, 0.0f);
    r.z = fmaxf(di * acc.z + b.z, 0.0f);
    r.w = fmaxf(di * acc.w + b.w, 0.0f);
    a1[(size_t)node * 32 + d4] = r;
}

// ---------------- gather layer 2 + FC + sigmoid ----------------
__global__ void gather2_k(const float2* __restrict__ hs, const int* __restrict__ rowptr,
                          const int* __restrict__ srcs, const float* __restrict__ dinv,
                          const float2* __restrict__ b2, const float2* __restrict__ Wfc,
                          const float* __restrict__ bfc, float* __restrict__ out) {
    int node = blockIdx.x * 8 + (threadIdx.x >> 5);
    int d2   = threadIdx.x & 31;
    if (node >= N_NODES) return;
    int beg = rowptr[node];
    int end = (node + 1 < N_NODES) ? rowptr[node + 1] : N_EDGES;
    float2 a0 = {0, 0}, a1v = {0, 0}, a2v = {0, 0}, a3v = {0, 0};
    int i = beg;
    for (; i + 4 <= end; i += 4) {
        int s0 = srcs[i], s1 = srcs[i + 1], s2 = srcs[i + 2], s3 = srcs[i + 3];
        float2 v0 = hs[(size_t)s0 * 32 + d2];
        float2 v1 = hs[(size_t)s1 * 32 + d2];
        float2 v2 = hs[(size_t)s2 * 32 + d2];
        float2 v3 = hs[(size_t)s3 * 32 + d2];
        a0.x += v0.x; a0.y += v0.y;
        a1v.x += v1.x; a1v.y += v1.y;
        a2v.x += v2.x; a2v.y += v2.y;
        a3v.x += v3.x; a3v.y += v3.y;
    }
    for (; i < end; ++i) {
        float2 v = hs[(size_t)srcs[i] * 32 + d2];
        a0.x += v.x; a0.y += v.y;
    }
    float2 vc = hs[(size_t)node * 32 + d2];
    float accx = a0.x + a1v.x + a2v.x + a3v.x + vc.x;
    float accy = a0.y + a1v.y + a2v.y + a3v.y + vc.y;
    float di = dinv[node];
    float2 b = b2[d2];
    float2 w = Wfc[d2];
    float vx = di * accx + b.x;
    float vy = di * accy + b.y;
    float p = vx * w.x + vy * w.y;
#pragma unroll
    for (int off = 16; off; off >>= 1) p += __shfl_down(p, off, 32);
    if (d2 == 0) out[node] = 1.0f / (1.0f + expf(-(p + bfc[0])));
}

extern "C" void kernel_launch(void* const* d_in, const int* in_sizes, int n_in,
                              void* d_out, int out_size, void* d_ws, size_t ws_size,
                              hipStream_t stream) {
    const float* x   = (const float*)d_in[0];
    const int*   ei  = (const int*)d_in[1];     // [2, E] int32
    const float* W1  = (const float*)d_in[2];
    const float* b1  = (const float*)d_in[3];
    const float* W2  = (const float*)d_in[4];
    const float* b2  = (const float*)d_in[5];
    const float* Wfc = (const float*)d_in[6];
    const float* bfc = (const float*)d_in[7];
    float* out = (float*)d_out;

    const int* rows = ei;             // sources
    const int* cols = ei + N_EDGES;   // targets

    // workspace layout (all 4-byte elements unless noted)
    float* ws     = (float*)d_ws;
    float* dinv   = ws;                                  // 50048
    int*   cnt    = (int*)(ws + 50048);                  // 50048 (later cursor)
    int*   rowptr = cnt + 50048;                         // 50048
    int*   bsum   = rowptr + 50048;                      // 64
    int*   srcs   = bsum + 64;                           // 800000
    float* h1     = (float*)(srcs + N_EDGES);            // 6.4M  (dinv-scaled)
    float* a1     = h1 + (size_t)N_NODES * D_HID;        // 6.4M
    float* h2     = a1 + (size_t)N_NODES * D_HID;        // 3.2M  (dinv-scaled)
    unsigned short* Wsw1 = (unsigned short*)(h2 + (size_t)N_NODES * D_ENC);  // 32768 us
    unsigned short* Wsw2 = Wsw1 + (size_t)D_IN * D_HID;                      // 8192 us

    const int NB = (N_NODES + SCAN_B - 1) / SCAN_B;      // 49

    // ---- CSR build ----
    hipMemsetAsync(cnt, 0, N_NODES * sizeof(int), stream);
    count_k<<<1024, 256, 0, stream>>>(cols, cnt);
    scan_block_k<<<NB, SCAN_B, 0, stream>>>(cnt, rowptr, bsum);
    scan_top_k<<<1, 64, 0, stream>>>(bsum, NB);
    scan_add_k<<<(N_NODES + 255) / 256, 256, 0, stream>>>(cnt, rowptr, bsum, dinv);
    fill_k<<<1024, 256, 0, stream>>>(rows, cols, cnt, srcs);

    // ---- weight swizzles (bf16 B-fragments) ----
    wsw_k<D_IN, D_HID><<<16, 256, 0, stream>>>(W1, Wsw1);    // 4096 frags
    wsw_k<D_HID, D_ENC><<<4, 256, 0, stream>>>(W2, Wsw2);    // 1024 frags

    // ---- layer 1 ----
    gemm_mfma_k<D_IN, D_HID><<<(N_NODES + 63) / 64, 256, 0, stream>>>(x, Wsw1, dinv, h1, N_NODES);
    gather1_k<<<(N_NODES + 7) / 8, 256, 0, stream>>>((const float4*)h1, rowptr, srcs, dinv,
                                                     (const float4*)b1, (float4*)a1);

    // ---- layer 2 + FC + sigmoid ----
    gemm_mfma_k<D_HID, D_ENC><<<(N_NODES + 63) / 64, 256, 0, stream>>>(a1, Wsw2, dinv, h2, N_NODES);
    gather2_k<<<(N_NODES + 7) / 8, 256, 0, stream>>>((const float2*)h2, rowptr, srcs, dinv,
                                                     (const float2*)b2, (const float2*)Wfc,
                                                     bfc, out);
}

// Round 5
// 291.949 us; speedup vs baseline: 2.7043x; 1.0880x over previous
//
#include <hip/hip_runtime.h>
#include <cmath>

#define N_NODES 50000
#define N_EDGES 800000
#define D_IN 256
#define D_HID 128
#define D_ENC 64
#define SCAN_B 1024
#define NBUK 64          // dest buckets, bucket = c >> 10 (49 used)
#define PB_EPT 8         // edges per thread in part_k

typedef short short8 __attribute__((ext_vector_type(8)));
typedef float floatx4 __attribute__((ext_vector_type(4)));
typedef unsigned short ushort8v __attribute__((ext_vector_type(8)));

static __device__ __forceinline__ unsigned short f2bf(float f) {
    unsigned int u = __float_as_uint(f);
    unsigned int r = (u + 0x7FFFu + ((u >> 16) & 1u)) >> 16;   // RNE
    return (unsigned short)r;
}
static __device__ __forceinline__ float bf2f(unsigned short u) {
    return __uint_as_float(((unsigned int)u) << 16);
}

// ---------------- count: per-node degree + per-bucket histogram ----------------
__global__ void count_k(const int* __restrict__ cols, int* __restrict__ cnt,
                        int* __restrict__ bcnt) {
    __shared__ int h[NBUK];
    if (threadIdx.x < NBUK) h[threadIdx.x] = 0;
    __syncthreads();
    int stride = gridDim.x * blockDim.x;
    for (int e = blockIdx.x * blockDim.x + threadIdx.x; e < N_EDGES; e += stride) {
        int c = cols[e];
        atomicAdd(&cnt[c], 1);
        atomicAdd(&h[c >> 10], 1);
    }
    __syncthreads();
    if (threadIdx.x < NBUK && h[threadIdx.x]) atomicAdd(&bcnt[threadIdx.x], h[threadIdx.x]);
}

__global__ void scan_block_k(const int* __restrict__ cnt, int* __restrict__ rowptr,
                             int* __restrict__ bsum) {
    __shared__ int s[SCAN_B];
    int i = blockIdx.x * SCAN_B + threadIdx.x;
    int v = (i < N_NODES) ? cnt[i] : 0;
    s[threadIdx.x] = v;
    __syncthreads();
    for (int off = 1; off < SCAN_B; off <<= 1) {
        int t = (threadIdx.x >= off) ? s[threadIdx.x - off] : 0;
        __syncthreads();
        s[threadIdx.x] += t;
        __syncthreads();
    }
    if (i < N_NODES) rowptr[i] = s[threadIdx.x] - v;   // exclusive
    if (threadIdx.x == SCAN_B - 1) bsum[blockIdx.x] = s[threadIdx.x];
}

// top-level scan of block sums + bucket-base scan (tiny, one thread)
__global__ void scan_top_k(int* __restrict__ bsum, int nb,
                           const int* __restrict__ bcnt, int* __restrict__ bcur) {
    if (blockIdx.x == 0 && threadIdx.x == 0) {
        int acc = 0;
        for (int i = 0; i < nb; ++i) { int v = bsum[i]; bsum[i] = acc; acc += v; }
        acc = 0;
        for (int i = 0; i < NBUK; ++i) { int v = bcnt[i]; bcur[i] = acc; acc += v; }
    }
}

__global__ void scan_add_k(int* __restrict__ cnt, int* __restrict__ rowptr,
                           const int* __restrict__ bsum, float* __restrict__ dinv) {
    int i = blockIdx.x * blockDim.x + threadIdx.x;
    if (i < N_NODES) {
        int rp = rowptr[i] + bsum[i / SCAN_B];
        rowptr[i] = rp;
        dinv[i] = rsqrtf((float)(cnt[i] + 1));   // +1 self-loop
        cnt[i] = rp;                              // becomes fill cursor
    }
}

// ---------------- radix partition: edges -> bucket-grouped (src,dst) ----------------
__global__ void part_k(const int* __restrict__ rows, const int* __restrict__ cols,
                       int* __restrict__ bcur, int2* __restrict__ bedges) {
    __shared__ int h[NBUK], base[NBUK];
    int e0 = blockIdx.x * (256 * PB_EPT);
    if (threadIdx.x < NBUK) h[threadIdx.x] = 0;
    __syncthreads();
    int src[PB_EPT], dst[PB_EPT];
#pragma unroll
    for (int j = 0; j < PB_EPT; ++j) {
        int e = e0 + j * 256 + threadIdx.x;
        if (e < N_EDGES) {
            src[j] = rows[e]; dst[j] = cols[e];
            atomicAdd(&h[dst[j] >> 10], 1);
        } else dst[j] = -1;
    }
    __syncthreads();
    if (threadIdx.x < NBUK) {
        int c = h[threadIdx.x];
        base[threadIdx.x] = c ? atomicAdd(&bcur[threadIdx.x], c) : 0;
        h[threadIdx.x] = 0;
    }
    __syncthreads();
#pragma unroll
    for (int j = 0; j < PB_EPT; ++j) {
        if (dst[j] >= 0) {
            int b = dst[j] >> 10;
            int r = atomicAdd(&h[b], 1);
            bedges[base[b] + r] = int2{src[j], dst[j]};
        }
    }
}

// ---------------- fill from bucketed edges (dest-local srcs writes) ----------------
__global__ void fill2_k(const int2* __restrict__ bedges, int* __restrict__ cursor,
                        int* __restrict__ srcs) {
    int stride = gridDim.x * blockDim.x;
    for (int e = blockIdx.x * blockDim.x + threadIdx.x; e < N_EDGES; e += stride) {
        int2 ed = bedges[e];
        int p = atomicAdd(&cursor[ed.y], 1);
        srcs[p] = ed.x;
    }
}

// ---------------- W pre-swizzle into B-fragment layout (bf16) ----------------
template<int K, int N>
__global__ void wsw_k(const float* __restrict__ W, unsigned short* __restrict__ Wsw) {
    constexpr int KS = K / 32, CT = N / 16;
    int t = blockIdx.x * blockDim.x + threadIdx.x;
    if (t >= CT * KS * 64) return;
    int lane = t & 63;
    int ks   = (t >> 6) % KS;
    int ct   = (t >> 6) / KS;
    int m = lane & 15, quad = lane >> 4;
    int kbase = ks * 32 + quad * 8;
    int col   = ct * 16 + m;
#pragma unroll
    for (int j = 0; j < 8; ++j)
        Wsw[t * 8 + j] = f2bf(W[(size_t)(kbase + j) * N + col]);
}

// ---------------- MFMA GEMM: H[r,:] = bf16(dinv[r] * (X[r,:] @ W)) ----------------
// IN_BF16: X is bf16 (ushort) rows; else fp32 converted during staging.
template<int K, int N, bool IN_BF16>
__global__ __launch_bounds__(256) void gemm_mfma_k(const void* __restrict__ Xv,
                                                   const unsigned short* __restrict__ Wsw,
                                                   const float* __restrict__ dinv,
                                                   unsigned short* __restrict__ H, int n) {
    constexpr int KS = K / 32, CT = N / 16, KP = K + 8;
    __shared__ unsigned short As[64 * KP];
    int row0 = blockIdx.x * 64;
    if (IN_BF16) {
        const ushort8v* X8 = (const ushort8v*)Xv;
        constexpr int NF8 = 64 * (K / 8);
        for (int idx = threadIdx.x; idx < NF8; idx += 256) {
            int r = idx / (K / 8), c8 = idx % (K / 8);
            int gr = row0 + r;
            ushort8v v = (gr < n) ? X8[(size_t)gr * (K / 8) + c8] : (ushort8v)0;
            *(ushort8v*)&As[r * KP + c8 * 8] = v;
        }
    } else {
        const float4* X4 = (const float4*)Xv;
        constexpr int NF4 = 64 * (K / 4);
        for (int idx = threadIdx.x; idx < NF4; idx += 256) {
            int r = idx / (K / 4), c4 = idx % (K / 4);
            int gr = row0 + r;
            float4 v = (gr < n) ? X4[(size_t)gr * (K / 4) + c4] : float4{0, 0, 0, 0};
            ushort4 p;
            p.x = f2bf(v.x); p.y = f2bf(v.y); p.z = f2bf(v.z); p.w = f2bf(v.w);
            *(ushort4*)&As[r * KP + c4 * 4] = p;
        }
    }
    __syncthreads();

    int w    = threadIdx.x >> 6;
    int lane = threadIdx.x & 63;
    int m    = lane & 15;
    int quad = lane >> 4;

    floatx4 acc[CT];
#pragma unroll
    for (int ct = 0; ct < CT; ++ct)
#pragma unroll
        for (int i = 0; i < 4; ++i) acc[ct][i] = 0.0f;

#pragma unroll
    for (int ks = 0; ks < KS; ++ks) {
        short8 af = *(const short8*)&As[(w * 16 + m) * KP + ks * 32 + quad * 8];
#pragma unroll
        for (int ct = 0; ct < CT; ++ct) {
            short8 bf = *(const short8*)&Wsw[(size_t)((ct * KS + ks) * 64 + lane) * 8];
            acc[ct] = __builtin_amdgcn_mfma_f32_16x16x32_bf16(af, bf, acc[ct], 0, 0, 0);
        }
    }

    int rbase = row0 + w * 16 + quad * 4;
    float dv[4];
#pragma unroll
    for (int reg = 0; reg < 4; ++reg) {
        int r = rbase + reg;
        dv[reg] = (r < n) ? dinv[r] : 0.0f;
    }
#pragma unroll
    for (int ct = 0; ct < CT; ++ct)
#pragma unroll
        for (int reg = 0; reg < 4; ++reg) {
            int r = rbase + reg;
            if (r < n) H[(size_t)r * N + ct * 16 + m] = f2bf(acc[ct][reg] * dv[reg]);
        }
}

// ---------------- gather layer 1: a1 = bf16(relu(di*(sum_s hs[s] + hs[c]) + b)) ----------------
// 32 lanes per node (ushort4 over 128 ch), 8 nodes per 256-block, unroll x4.
__global__ void gather1_k(const ushort4* __restrict__ hs, const int* __restrict__ rowptr,
                          const int* __restrict__ srcs, const float* __restrict__ dinv,
                          const float4* __restrict__ b4, ushort4* __restrict__ a1o) {
    int node = blockIdx.x * 8 + (threadIdx.x >> 5);
    int d4   = threadIdx.x & 31;
    if (node >= N_NODES) return;
    int beg = rowptr[node];
    int end = (node + 1 < N_NODES) ? rowptr[node + 1] : N_EDGES;
    float4 a0 = {0, 0, 0, 0}, a1v = {0, 0, 0, 0}, a2v = {0, 0, 0, 0}, a3v = {0, 0, 0, 0};
    int i = beg;
    for (; i + 4 <= end; i += 4) {
        int s0 = srcs[i], s1 = srcs[i + 1], s2 = srcs[i + 2], s3 = srcs[i + 3];
        ushort4 u0 = hs[(size_t)s0 * 32 + d4];
        ushort4 u1 = hs[(size_t)s1 * 32 + d4];
        ushort4 u2 = hs[(size_t)s2 * 32 + d4];
        ushort4 u3 = hs[(size_t)s3 * 32 + d4];
        a0.x += bf2f(u0.x); a0.y += bf2f(u0.y); a0.z += bf2f(u0.z); a0.w += bf2f(u0.w);
        a1v.x += bf2f(u1.x); a1v.y += bf2f(u1.y); a1v.z += bf2f(u1.z); a1v.w += bf2f(u1.w);
        a2v.x += bf2f(u2.x); a2v.y += bf2f(u2.y); a2v.z += bf2f(u2.z); a2v.w += bf2f(u2.w);
        a3v.x += bf2f(u3.x); a3v.y += bf2f(u3.y); a3v.z += bf2f(u3.z); a3v.w += bf2f(u3.w);
    }
    for (; i < end; ++i) {
        ushort4 u = hs[(size_t)srcs[i] * 32 + d4];
        a0.x += bf2f(u.x); a0.y += bf2f(u.y); a0.z += bf2f(u.z); a0.w += bf2f(u.w);
    }
    ushort4 uc = hs[(size_t)node * 32 + d4];   // self-loop (already dinv-scaled)
    float4 acc;
    acc.x = a0.x + a1v.x + a2v.x + a3v.x + bf2f(uc.x);
    acc.y = a0.y + a1v.y + a2v.y + a3v.y + bf2f(uc.y);
    acc.z = a0.z + a1v.z + a2v.z + a3v.z + bf2f(uc.z);
    acc.w = a0.w + a1v.w + a2v.w + a3v.w + bf2f(uc.w);
    float di = dinv[node];
    float4 b = b4[d4];
    ushort4 r;
    r.x = f2bf(fmaxf(di * acc.x + b.x, 0.0f));
    r.y = f2bf(fmaxf(di * acc.y + b.y, 0.0f));
    r.z = f2bf(fmaxf(di * acc.z + b.z, 0.0f));
    r.w = f2bf(fmaxf(di * acc.w + b.w, 0.0f));
    a1o[(size_t)node * 32 + d4] = r;
}

// ---------------- gather layer 2 + FC + sigmoid ----------------
// 16 lanes per node (ushort4 over 64 ch), 16 nodes per 256-block, unroll x4.
__global__ void gather2_k(const ushort4* __restrict__ hs, const int* __restrict__ rowptr,
                          const int* __restrict__ srcs, const float* __restrict__ dinv,
                          const float4* __restrict__ b4, const float4* __restrict__ Wfc4,
                          const float* __restrict__ bfc, float* __restrict__ out) {
    int node = blockIdx.x * 16 + (threadIdx.x >> 4);
    int d4   = threadIdx.x & 15;
    if (node >= N_NODES) return;
    int beg = rowptr[node];
    int end = (node + 1 < N_NODES) ? rowptr[node + 1] : N_EDGES;
    float4 a0 = {0, 0, 0, 0}, a1v = {0, 0, 0, 0}, a2v = {0, 0, 0, 0}, a3v = {0, 0, 0, 0};
    int i = beg;
    for (; i + 4 <= end; i += 4) {
        int s0 = srcs[i], s1 = srcs[i + 1], s2 = srcs[i + 2], s3 = srcs[i + 3];
        ushort4 u0 = hs[(size_t)s0 * 16 + d4];
        ushort4 u1 = hs[(size_t)s1 * 16 + d4];
        ushort4 u2 = hs[(size_t)s2 * 16 + d4];
        ushort4 u3 = hs[(size_t)s3 * 16 + d4];
        a0.x += bf2f(u0.x); a0.y += bf2f(u0.y); a0.z += bf2f(u0.z); a0.w += bf2f(u0.w);
        a1v.x += bf2f(u1.x); a1v.y += bf2f(u1.y); a1v.z += bf2f(u1.z); a1v.w += bf2f(u1.w);
        a2v.x += bf2f(u2.x); a2v.y += bf2f(u2.y); a2v.z += bf2f(u2.z); a2v.w += bf2f(u2.w);
        a3v.x += bf2f(u3.x); a3v.y += bf2f(u3.y); a3v.z += bf2f(u3.z); a3v.w += bf2f(u3.w);
    }
    for (; i < end; ++i) {
        ushort4 u = hs[(size_t)srcs[i] * 16 + d4];
        a0.x += bf2f(u.x); a0.y += bf2f(u.y); a0.z += bf2f(u.z); a0.w += bf2f(u.w);
    }
    ushort4 uc = hs[(size_t)node * 16 + d4];
    float di = dinv[node];
    float4 b = b4[d4];
    float4 w = Wfc4[d4];
    float vx = di * (a0.x + a1v.x + a2v.x + a3v.x + bf2f(uc.x)) + b.x;
    float vy = di * (a0.y + a1v.y + a2v.y + a3v.y + bf2f(uc.y)) + b.y;
    float vz = di * (a0.z + a1v.z + a2v.z + a3v.z + bf2f(uc.z)) + b.z;
    float vw = di * (a0.w + a1v.w + a2v.w + a3v.w + bf2f(uc.w)) + b.w;
    float p = vx * w.x + vy * w.y + vz * w.z + vw * w.w;
#pragma unroll
    for (int off = 8; off; off >>= 1) p += __shfl_down(p, off, 16);
    if (d4 == 0) out[node] = 1.0f / (1.0f + expf(-(p + bfc[0])));
}

extern "C" void kernel_launch(void* const* d_in, const int* in_sizes, int n_in,
                              void* d_out, int out_size, void* d_ws, size_t ws_size,
                              hipStream_t stream) {
    const float* x   = (const float*)d_in[0];
    const int*   ei  = (const int*)d_in[1];     // [2, E] int32
    const float* W1  = (const float*)d_in[2];
    const float* b1  = (const float*)d_in[3];
    const float* W2  = (const float*)d_in[4];
    const float* b2  = (const float*)d_in[5];
    const float* Wfc = (const float*)d_in[6];
    const float* bfc = (const float*)d_in[7];
    float* out = (float*)d_out;

    const int* rows = ei;             // sources
    const int* cols = ei + N_EDGES;   // targets

    // workspace layout (4-byte units; 16B alignment kept for vector types)
    float* ws     = (float*)d_ws;
    float* dinv   = ws;                                   // [0, 50048)
    int*   cnt    = (int*)(ws + 50048);                   // 50048 (later cursor)
    int*   rowptr = cnt + 50048;                          // 50048
    int*   bsum   = rowptr + 50048;                       // 64
    int*   bcnt   = bsum + 64;                            // 64
    int*   bcur   = bcnt + 64;                            // 64
    int*   srcs   = bcur + 64;                            // 800000
    int2*  bedges = (int2*)(srcs + N_EDGES);              // 800000 int2
    unsigned short* h1 = (unsigned short*)(bedges + N_EDGES);      // 6.4M us
    unsigned short* a1 = h1 + (size_t)N_NODES * D_HID;             // 6.4M us
    unsigned short* h2 = a1 + (size_t)N_NODES * D_HID;             // 3.2M us
    unsigned short* Wsw1 = h2 + (size_t)N_NODES * D_ENC;           // 32768 us
    unsigned short* Wsw2 = Wsw1 + (size_t)D_IN * D_HID;            // 8192 us

    const int NB = (N_NODES + SCAN_B - 1) / SCAN_B;       // 49

    // ---- CSR build (radix-partitioned fill) ----
    hipMemsetAsync(cnt, 0, (50048 + 50048 + 64 + 64 + 64) * sizeof(int), stream);
    count_k<<<1024, 256, 0, stream>>>(cols, cnt, bcnt);
    scan_block_k<<<NB, SCAN_B, 0, stream>>>(cnt, rowptr, bsum);
    scan_top_k<<<1, 64, 0, stream>>>(bsum, NB, bcnt, bcur);
    scan_add_k<<<(N_NODES + 255) / 256, 256, 0, stream>>>(cnt, rowptr, bsum, dinv);
    part_k<<<(N_EDGES + 256 * PB_EPT - 1) / (256 * PB_EPT), 256, 0, stream>>>(rows, cols, bcur, bedges);
    fill2_k<<<512, 256, 0, stream>>>(bedges, cnt, srcs);

    // ---- weight swizzles (bf16 B-fragments) ----
    wsw_k<D_IN, D_HID><<<16, 256, 0, stream>>>(W1, Wsw1);
    wsw_k<D_HID, D_ENC><<<4, 256, 0, stream>>>(W2, Wsw2);

    // ---- layer 1 ----
    gemm_mfma_k<D_IN, D_HID, false><<<(N_NODES + 63) / 64, 256, 0, stream>>>(x, Wsw1, dinv, h1, N_NODES);
    gather1_k<<<(N_NODES + 7) / 8, 256, 0, stream>>>((const ushort4*)h1, rowptr, srcs, dinv,
                                                     (const float4*)b1, (ushort4*)a1);

    // ---- layer 2 + FC + sigmoid ----
    gemm_mfma_k<D_HID, D_ENC, true><<<(N_NODES + 63) / 64, 256, 0, stream>>>(a1, Wsw2, dinv, h2, N_NODES);
    gather2_k<<<(N_NODES + 15) / 16, 256, 0, stream>>>((const ushort4*)h2, rowptr, srcs, dinv,
                                                       (const float4*)b2, (const float4*)Wfc,
                                                       bfc, out);
}

// Round 6
// 236.064 us; speedup vs baseline: 3.3445x; 1.2367x over previous
//
#include <hip/hip_runtime.h>
#include <cmath>

#define N_NODES 50000
#define N_EDGES 800000
#define D_IN 256
#define D_HID 128
#define D_ENC 64
#define NBUK 64          // dest buckets, bucket = c >> 10 (49 used)
#define PB_EPT 8         // edges per thread in part_k

typedef short short8 __attribute__((ext_vector_type(8)));
typedef float floatx4 __attribute__((ext_vector_type(4)));
typedef unsigned short ushort8v __attribute__((ext_vector_type(8)));

static __device__ __forceinline__ unsigned short f2bf(float f) {
    unsigned int u = __float_as_uint(f);
    unsigned int r = (u + 0x7FFFu + ((u >> 16) & 1u)) >> 16;   // RNE
    return (unsigned short)r;
}
static __device__ __forceinline__ float bf2f(unsigned short u) {
    return __uint_as_float(((unsigned int)u) << 16);
}

// ---------------- bucket histogram only (no per-node atomics) ----------------
__global__ void bhist_k(const int* __restrict__ cols, int* __restrict__ bcnt) {
    __shared__ int h[NBUK];
    if (threadIdx.x < NBUK) h[threadIdx.x] = 0;
    __syncthreads();
    int stride = gridDim.x * blockDim.x;
    for (int e = blockIdx.x * blockDim.x + threadIdx.x; e < N_EDGES; e += stride)
        atomicAdd(&h[cols[e] >> 10], 1);
    __syncthreads();
    if (threadIdx.x < NBUK && h[threadIdx.x]) atomicAdd(&bcnt[threadIdx.x], h[threadIdx.x]);
}

// bucket exclusive scan -> bstart[NBUK+1], bcur (part_k cursor copy)
__global__ void scan_top_k(const int* __restrict__ bcnt, int* __restrict__ bstart,
                           int* __restrict__ bcur) {
    if (blockIdx.x == 0 && threadIdx.x == 0) {
        int acc = 0;
        for (int i = 0; i < NBUK; ++i) {
            bstart[i] = acc; bcur[i] = acc; acc += bcnt[i];
        }
        bstart[NBUK] = acc;
    }
}

// ---------------- radix partition: edges -> bucket-grouped (src,dst) ----------------
__global__ void part_k(const int* __restrict__ rows, const int* __restrict__ cols,
                       int* __restrict__ bcur, int2* __restrict__ bedges) {
    __shared__ int h[NBUK], base[NBUK];
    int e0 = blockIdx.x * (256 * PB_EPT);
    if (threadIdx.x < NBUK) h[threadIdx.x] = 0;
    __syncthreads();
    int src[PB_EPT], dst[PB_EPT];
#pragma unroll
    for (int j = 0; j < PB_EPT; ++j) {
        int e = e0 + j * 256 + threadIdx.x;
        if (e < N_EDGES) {
            src[j] = rows[e]; dst[j] = cols[e];
            atomicAdd(&h[dst[j] >> 10], 1);
        } else dst[j] = -1;
    }
    __syncthreads();
    if (threadIdx.x < NBUK) {
        int c = h[threadIdx.x];
        base[threadIdx.x] = c ? atomicAdd(&bcur[threadIdx.x], c) : 0;
        h[threadIdx.x] = 0;
    }
    __syncthreads();
#pragma unroll
    for (int j = 0; j < PB_EPT; ++j) {
        if (dst[j] >= 0) {
            int b = dst[j] >> 10;
            int r = atomicAdd(&h[b], 1);
            bedges[base[b] + r] = int2{src[j], dst[j]};
        }
    }
}

// ---------------- per-bucket CSR: count+scan+dinv+fill, all in LDS ----------------
__global__ __launch_bounds__(1024) void bucket_csr_k(const int2* __restrict__ bedges,
                                                     const int* __restrict__ bstart,
                                                     int* __restrict__ rowptr,
                                                     int* __restrict__ srcs,
                                                     float* __restrict__ dinv) {
    __shared__ int s[1024];
    __shared__ int cur[1024];
    int b = blockIdx.x;
    int ebeg = bstart[b], eend = bstart[b + 1];
    int tid = threadIdx.x;
    s[tid] = 0;
    __syncthreads();
    for (int e = ebeg + tid; e < eend; e += 1024)
        atomicAdd(&s[bedges[e].y & 1023], 1);
    __syncthreads();
    int v = s[tid];
    // inclusive block scan (read-barrier-write pattern)
    for (int off = 1; off < 1024; off <<= 1) {
        int t = (tid >= off) ? s[tid - off] : 0;
        __syncthreads();
        s[tid] += t;
        __syncthreads();
    }
    int excl = s[tid] - v;
    cur[tid] = excl;
    int node = (b << 10) + tid;
    if (node < N_NODES) {
        rowptr[node] = ebeg + excl;
        dinv[node] = rsqrtf((float)(v + 1));   // +1 self-loop
    }
    __syncthreads();
    for (int e = ebeg + tid; e < eend; e += 1024) {
        int2 ed = bedges[e];
        int p = atomicAdd(&cur[ed.y & 1023], 1);
        srcs[ebeg + p] = ed.x;
    }
}

// ---------------- W pre-swizzle into B-fragment layout (bf16), both weights ----------------
static __device__ __forceinline__ void wswz(const float* __restrict__ W,
                                            unsigned short* __restrict__ Wsw,
                                            int t, int K, int N) {
    int KS = K / 32;
    int lane = t & 63;
    int ks   = (t >> 6) % KS;
    int ct   = (t >> 6) / KS;
    int m = lane & 15, quad = lane >> 4;
    int kbase = ks * 32 + quad * 8;
    int col   = ct * 16 + m;
#pragma unroll
    for (int j = 0; j < 8; ++j)
        Wsw[t * 8 + j] = f2bf(W[(size_t)(kbase + j) * N + col]);
}

__global__ void wsw_all_k(const float* __restrict__ W1, const float* __restrict__ W2,
                          unsigned short* __restrict__ Wsw1, unsigned short* __restrict__ Wsw2) {
    int t = blockIdx.x * blockDim.x + threadIdx.x;
    if (t < 4096) wswz(W1, Wsw1, t, D_IN, D_HID);            // 8*8*64 frags*lanes
    else if (t < 4096 + 1024) wswz(W2, Wsw2, t - 4096, D_HID, D_ENC);
}

// ---------------- MFMA GEMM: H[r,:] = bf16(dinv[r] * (X[r,:] @ W)) ----------------
template<int K, int N, bool IN_BF16>
__global__ __launch_bounds__(256) void gemm_mfma_k(const void* __restrict__ Xv,
                                                   const unsigned short* __restrict__ Wsw,
                                                   const float* __restrict__ dinv,
                                                   unsigned short* __restrict__ H, int n) {
    constexpr int KS = K / 32, CT = N / 16, KP = K + 8;
    __shared__ unsigned short As[64 * KP];
    int row0 = blockIdx.x * 64;
    if (IN_BF16) {
        const ushort8v* X8 = (const ushort8v*)Xv;
        constexpr int NF8 = 64 * (K / 8);
        for (int idx = threadIdx.x; idx < NF8; idx += 256) {
            int r = idx / (K / 8), c8 = idx % (K / 8);
            int gr = row0 + r;
            ushort8v v = (gr < n) ? X8[(size_t)gr * (K / 8) + c8] : (ushort8v)0;
            *(ushort8v*)&As[r * KP + c8 * 8] = v;
        }
    } else {
        const float4* X4 = (const float4*)Xv;
        constexpr int NF4 = 64 * (K / 4);
        for (int idx = threadIdx.x; idx < NF4; idx += 256) {
            int r = idx / (K / 4), c4 = idx % (K / 4);
            int gr = row0 + r;
            float4 v = (gr < n) ? X4[(size_t)gr * (K / 4) + c4] : float4{0, 0, 0, 0};
            ushort4 p;
            p.x = f2bf(v.x); p.y = f2bf(v.y); p.z = f2bf(v.z); p.w = f2bf(v.w);
            *(ushort4*)&As[r * KP + c4 * 4] = p;
        }
    }
    __syncthreads();

    int w    = threadIdx.x >> 6;
    int lane = threadIdx.x & 63;
    int m    = lane & 15;
    int quad = lane >> 4;

    floatx4 acc[CT];
#pragma unroll
    for (int ct = 0; ct < CT; ++ct)
#pragma unroll
        for (int i = 0; i < 4; ++i) acc[ct][i] = 0.0f;

#pragma unroll
    for (int ks = 0; ks < KS; ++ks) {
        short8 af = *(const short8*)&As[(w * 16 + m) * KP + ks * 32 + quad * 8];
#pragma unroll
        for (int ct = 0; ct < CT; ++ct) {
            short8 bf = *(const short8*)&Wsw[(size_t)((ct * KS + ks) * 64 + lane) * 8];
            acc[ct] = __builtin_amdgcn_mfma_f32_16x16x32_bf16(af, bf, acc[ct], 0, 0, 0);
        }
    }

    int rbase = row0 + w * 16 + quad * 4;
    float dv[4];
#pragma unroll
    for (int reg = 0; reg < 4; ++reg) {
        int r = rbase + reg;
        dv[reg] = (r < n) ? dinv[r] : 0.0f;
    }
#pragma unroll
    for (int ct = 0; ct < CT; ++ct)
#pragma unroll
        for (int reg = 0; reg < 4; ++reg) {
            int r = rbase + reg;
            if (r < n) H[(size_t)r * N + ct * 16 + m] = f2bf(acc[ct][reg] * dv[reg]);
        }
}

// ---------------- gather layer 1: a1 = bf16(relu(di*(sum_s hs[s] + hs[c]) + b)) ----------------
__global__ void gather1_k(const ushort4* __restrict__ hs, const int* __restrict__ rowptr,
                          const int* __restrict__ srcs, const float* __restrict__ dinv,
                          const float4* __restrict__ b4, ushort4* __restrict__ a1o) {
    int node = blockIdx.x * 8 + (threadIdx.x >> 5);
    int d4   = threadIdx.x & 31;
    if (node >= N_NODES) return;
    int beg = rowptr[node];
    int end = (node + 1 < N_NODES) ? rowptr[node + 1] : N_EDGES;
    float4 a0 = {0, 0, 0, 0}, a1v = {0, 0, 0, 0}, a2v = {0, 0, 0, 0}, a3v = {0, 0, 0, 0};
    int i = beg;
    for (; i + 4 <= end; i += 4) {
        int s0 = srcs[i], s1 = srcs[i + 1], s2 = srcs[i + 2], s3 = srcs[i + 3];
        ushort4 u0 = hs[(size_t)s0 * 32 + d4];
        ushort4 u1 = hs[(size_t)s1 * 32 + d4];
        ushort4 u2 = hs[(size_t)s2 * 32 + d4];
        ushort4 u3 = hs[(size_t)s3 * 32 + d4];
        a0.x += bf2f(u0.x); a0.y += bf2f(u0.y); a0.z += bf2f(u0.z); a0.w += bf2f(u0.w);
        a1v.x += bf2f(u1.x); a1v.y += bf2f(u1.y); a1v.z += bf2f(u1.z); a1v.w += bf2f(u1.w);
        a2v.x += bf2f(u2.x); a2v.y += bf2f(u2.y); a2v.z += bf2f(u2.z); a2v.w += bf2f(u2.w);
        a3v.x += bf2f(u3.x); a3v.y += bf2f(u3.y); a3v.z += bf2f(u3.z); a3v.w += bf2f(u3.w);
    }
    for (; i < end; ++i) {
        ushort4 u = hs[(size_t)srcs[i] * 32 + d4];
        a0.x += bf2f(u.x); a0.y += bf2f(u.y); a0.z += bf2f(u.z); a0.w += bf2f(u.w);
    }
    ushort4 uc = hs[(size_t)node * 32 + d4];   // self-loop (already dinv-scaled)
    float4 acc;
    acc.x = a0.x + a1v.x + a2v.x + bf2f(uc.x) + a3v.x;
    acc.y = a0.y + a1v.y + a2v.y + bf2f(uc.y) + a3v.y;
    acc.z = a0.z + a1v.z + a2v.z + bf2f(uc.z) + a3v.z;
    acc.w = a0.w + a1v.w + a2v.w + bf2f(uc.w) + a3v.w;
    float di = dinv[node];
    float4 b = b4[d4];
    ushort4 r;
    r.x = f2bf(fmaxf(di * acc.x + b.x, 0.0f));
    r.y = f2bf(fmaxf(di * acc.y + b.y, 0.0f));
    r.z = f2bf(fmaxf(di * acc.z + b.z, 0.0f));
    r.w = f2bf(fmaxf(di * acc.w + b.w, 0.0f));
    a1o[(size_t)node * 32 + d4] = r;
}

// ---------------- gather layer 2 + FC + sigmoid ----------------
__global__ void gather2_k(const ushort4* __restrict__ hs, const int* __restrict__ rowptr,
                          const int* __restrict__ srcs, const float* __restrict__ dinv,
                          const float4* __restrict__ b4, const float4* __restrict__ Wfc4,
                          const float* __restrict__ bfc, float* __restrict__ out) {
    int node = blockIdx.x * 16 + (threadIdx.x >> 4);
    int d4   = threadIdx.x & 15;
    if (node >= N_NODES) return;
    int beg = rowptr[node];
    int end = (node + 1 < N_NODES) ? rowptr[node + 1] : N_EDGES;
    float4 a0 = {0, 0, 0, 0}, a1v = {0, 0, 0, 0}, a2v = {0, 0, 0, 0}, a3v = {0, 0, 0, 0};
    int i = beg;
    for (; i + 4 <= end; i += 4) {
        int s0 = srcs[i], s1 = srcs[i + 1], s2 = srcs[i + 2], s3 = srcs[i + 3];
        ushort4 u0 = hs[(size_t)s0 * 16 + d4];
        ushort4 u1 = hs[(size_t)s1 * 16 + d4];
        ushort4 u2 = hs[(size_t)s2 * 16 + d4];
        ushort4 u3 = hs[(size_t)s3 * 16 + d4];
        a0.x += bf2f(u0.x); a0.y += bf2f(u0.y); a0.z += bf2f(u0.z); a0.w += bf2f(u0.w);
        a1v.x += bf2f(u1.x); a1v.y += bf2f(u1.y); a1v.z += bf2f(u1.z); a1v.w += bf2f(u1.w);
        a2v.x += bf2f(u2.x); a2v.y += bf2f(u2.y); a2v.z += bf2f(u2.z); a2v.w += bf2f(u2.w);
        a3v.x += bf2f(u3.x); a3v.y += bf2f(u3.y); a3v.z += bf2f(u3.z); a3v.w += bf2f(u3.w);
    }
    for (; i < end; ++i) {
        ushort4 u = hs[(size_t)srcs[i] * 16 + d4];
        a0.x += bf2f(u.x); a0.y += bf2f(u.y); a0.z += bf2f(u.z); a0.w += bf2f(u.w);
    }
    ushort4 uc = hs[(size_t)node * 16 + d4];
    float di = dinv[node];
    float4 b = b4[d4];
    float4 w = Wfc4[d4];
    float vx = di * (a0.x + a1v.x + a2v.x + a3v.x + bf2f(uc.x)) + b.x;
    float vy = di * (a0.y + a1v.y + a2v.y + a3v.y + bf2f(uc.y)) + b.y;
    float vz = di * (a0.z + a1v.z + a2v.z + a3v.z + bf2f(uc.z)) + b.z;
    float vw = di * (a0.w + a1v.w + a2v.w + a3v.w + bf2f(uc.w)) + b.w;
    float p = vx * w.x + vy * w.y + vz * w.z + vw * w.w;
#pragma unroll
    for (int off = 8; off; off >>= 1) p += __shfl_down(p, off, 16);
    if (d4 == 0) out[node] = 1.0f / (1.0f + expf(-(p + bfc[0])));
}

extern "C" void kernel_launch(void* const* d_in, const int* in_sizes, int n_in,
                              void* d_out, int out_size, void* d_ws, size_t ws_size,
                              hipStream_t stream) {
    const float* x   = (const float*)d_in[0];
    const int*   ei  = (const int*)d_in[1];     // [2, E] int32
    const float* W1  = (const float*)d_in[2];
    const float* b1  = (const float*)d_in[3];
    const float* W2  = (const float*)d_in[4];
    const float* b2  = (const float*)d_in[5];
    const float* Wfc = (const float*)d_in[6];
    const float* bfc = (const float*)d_in[7];
    float* out = (float*)d_out;

    const int* rows = ei;             // sources
    const int* cols = ei + N_EDGES;   // targets

    // workspace layout (4-byte units; 16B alignment kept for vector types)
    float* ws     = (float*)d_ws;
    float* dinv   = ws;                                   // 50048
    int*   rowptr = (int*)(ws + 50048);                   // 50048
    int*   bcnt   = rowptr + 50048;                       // 64
    int*   bcur   = bcnt + 64;                            // 64
    int*   bstart = bcur + 64;                            // 65 (+pad to 96)
    int*   srcs   = bstart + 96;                          // 800000
    int2*  bedges = (int2*)(srcs + N_EDGES);              // 800000 int2
    unsigned short* h1 = (unsigned short*)(bedges + N_EDGES);      // 6.4M us
    unsigned short* a1 = h1 + (size_t)N_NODES * D_HID;             // 6.4M us
    unsigned short* h2 = a1 + (size_t)N_NODES * D_HID;             // 3.2M us
    unsigned short* Wsw1 = h2 + (size_t)N_NODES * D_ENC;           // 32768 us
    unsigned short* Wsw2 = Wsw1 + (size_t)D_IN * D_HID;            // 8192 us

    // ---- CSR build (bucket-local counting sort, no per-node global atomics) ----
    hipMemsetAsync(bcnt, 0, NBUK * sizeof(int), stream);
    bhist_k<<<1024, 256, 0, stream>>>(cols, bcnt);
    scan_top_k<<<1, 64, 0, stream>>>(bcnt, bstart, bcur);
    part_k<<<(N_EDGES + 256 * PB_EPT - 1) / (256 * PB_EPT), 256, 0, stream>>>(rows, cols, bcur, bedges);
    bucket_csr_k<<<(N_NODES + 1023) / 1024, 1024, 0, stream>>>(bedges, bstart, rowptr, srcs, dinv);

    // ---- weight swizzles (bf16 B-fragments) ----
    wsw_all_k<<<20, 256, 0, stream>>>(W1, W2, Wsw1, Wsw2);

    // ---- layer 1 ----
    gemm_mfma_k<D_IN, D_HID, false><<<(N_NODES + 63) / 64, 256, 0, stream>>>(x, Wsw1, dinv, h1, N_NODES);
    gather1_k<<<(N_NODES + 7) / 8, 256, 0, stream>>>((const ushort4*)h1, rowptr, srcs, dinv,
                                                     (const float4*)b1, (ushort4*)a1);

    // ---- layer 2 + FC + sigmoid ----
    gemm_mfma_k<D_HID, D_ENC, true><<<(N_NODES + 63) / 64, 256, 0, stream>>>(a1, Wsw2, dinv, h2, N_NODES);
    gather2_k<<<(N_NODES + 15) / 16, 256, 0, stream>>>((const ushort4*)h2, rowptr, srcs, dinv,
                                                       (const float4*)b2, (const float4*)Wfc,
                                                       bfc, out);
}